// Round 1
// baseline (2695.471 us; speedup 1.0000x reference)
//
#include <hip/hip_runtime.h>

// Problem constants
#define HH 64          // H
#define WW 128         // W
#define DD 48          // max disparity
#define GG 32          // groups (= conv channels)
#define CG 8           // channels per group
#define CIN 256        // input feature channels
#define HID 32         // hidden channels
#define SPATIAL (DD*HH*WW)          // 393216
#define VOL_ELEMS ((size_t)SPATIAL*GG)  // 12,582,912 floats per volume

// ---------------------------------------------------------------------------
// Weight transpose: src [O][I][3][3][3] -> dst [tap][I][O]  (tap = kz*9+ky*3+kx)
// dst[(tap*I + ci)*O + co] = src[(co*I + ci)*27 + tap]
// ---------------------------------------------------------------------------
__global__ void transpose_w_kernel(const float* __restrict__ src,
                                   float* __restrict__ dst, int O, int I) {
    int tid = blockIdx.x * 256 + threadIdx.x;
    int total = O * I * 27;
    if (tid >= total) return;
    int co  = tid % O;
    int rem = tid / O;
    int ci  = rem % I;
    int tap = rem / I;
    dst[tid] = src[(co * I + ci) * 27 + tap];
}

// ---------------------------------------------------------------------------
// Cost volume, channels-last: vol[((d*H + h)*W + w)*32 + g]
//   = (1/8) * sum_cc left[g*8+cc][h][w] * right[g*8+cc][h][w-d]   (0 if w<d)
// One thread per (g,h,w); thread keeps acc[48] (one per disparity).
// ---------------------------------------------------------------------------
__global__ void build_vol_kernel(const float* __restrict__ L,
                                 const float* __restrict__ R,
                                 float* __restrict__ vol) {
    int w = threadIdx.x;      // 0..127
    int h = blockIdx.x;       // 0..63
    int g = blockIdx.y;       // 0..31

    const float* lp = L + (size_t)(g * CG) * HH * WW + h * WW + w;
    const float* rp = R + (size_t)(g * CG) * HH * WW + h * WW;

    float acc[DD];
#pragma unroll
    for (int d = 0; d < DD; ++d) acc[d] = 0.f;

    int dmax = (w + 1 < DD) ? (w + 1) : DD;
#pragma unroll
    for (int cc = 0; cc < CG; ++cc) {
        float lv = lp[(size_t)cc * HH * WW];
        const float* r = rp + (size_t)cc * HH * WW;
        for (int d = 0; d < dmax; ++d) acc[d] += lv * r[w - d];
    }

    float* out = vol + ((size_t)h * WW + w) * GG + g;
#pragma unroll
    for (int d = 0; d < DD; ++d)
        out[(size_t)d * HH * WW * GG] = acc[d] * 0.125f;
}

// ---------------------------------------------------------------------------
// 3x3x3 conv, 32ch -> 32ch, channels-last, optional leaky-relu(0.2).
// X: [D][H][W][32], Wt: [27][32ci][32co], Y: [D][H][W][32]
// One thread per spatial point, 32 accumulators.
// ---------------------------------------------------------------------------
__global__ __launch_bounds__(256) void conv3d_lrelu_kernel(
    const float* __restrict__ X, const float* __restrict__ Wt,
    const float* __restrict__ bias, float* __restrict__ Y, int apply_relu) {
    int s = blockIdx.x * 256 + threadIdx.x;
    if (s >= SPATIAL) return;
    int w = s & (WW - 1);
    int h = (s >> 7) & (HH - 1);
    int d = s >> 13;

    float acc[HID];
#pragma unroll
    for (int i = 0; i < HID; ++i) acc[i] = bias[i];

    for (int dd = -1; dd <= 1; ++dd) {
        int z = d + dd;
        if (z < 0 || z >= DD) continue;
        for (int dh = -1; dh <= 1; ++dh) {
            int y = h + dh;
            if (y < 0 || y >= HH) continue;
            for (int dw = -1; dw <= 1; ++dw) {
                int x = w + dw;
                if (x < 0 || x >= WW) continue;
                int tap = (dd + 1) * 9 + (dh + 1) * 3 + (dw + 1);
                const float4* xp =
                    (const float4*)(X + (((size_t)z * HH + y) * WW + x) * GG);
                const float* wp = Wt + (size_t)tap * GG * HID;

                float xv[GG];
#pragma unroll
                for (int i = 0; i < GG / 4; ++i) {
                    float4 t = xp[i];
                    xv[i * 4 + 0] = t.x; xv[i * 4 + 1] = t.y;
                    xv[i * 4 + 2] = t.z; xv[i * 4 + 3] = t.w;
                }
#pragma unroll
                for (int ci = 0; ci < GG; ++ci) {
                    float v = xv[ci];
                    const float4* wr = (const float4*)(wp + (size_t)ci * HID);
#pragma unroll
                    for (int q = 0; q < HID / 4; ++q) {
                        float4 wv = wr[q];
                        acc[q * 4 + 0] += v * wv.x;
                        acc[q * 4 + 1] += v * wv.y;
                        acc[q * 4 + 2] += v * wv.z;
                        acc[q * 4 + 3] += v * wv.w;
                    }
                }
            }
        }
    }

    float* yp = Y + (size_t)s * HID;
#pragma unroll
    for (int i = 0; i < HID; ++i) {
        float v = acc[i];
        if (apply_relu) v = fmaxf(v, 0.f) + 0.2f * fminf(v, 0.f);
        yp[i] = v;
    }
}

// ---------------------------------------------------------------------------
// Final 3x3x3 conv, 32ch -> 1ch. WfT: [27][32], out: [D][H][W] (flat f32)
// ---------------------------------------------------------------------------
__global__ __launch_bounds__(256) void conv3d_final_kernel(
    const float* __restrict__ X, const float* __restrict__ WfT,
    const float* __restrict__ bias, float* __restrict__ Y) {
    int s = blockIdx.x * 256 + threadIdx.x;
    if (s >= SPATIAL) return;
    int w = s & (WW - 1);
    int h = (s >> 7) & (HH - 1);
    int d = s >> 13;

    float acc = bias[0];
    for (int dd = -1; dd <= 1; ++dd) {
        int z = d + dd;
        if (z < 0 || z >= DD) continue;
        for (int dh = -1; dh <= 1; ++dh) {
            int y = h + dh;
            if (y < 0 || y >= HH) continue;
            for (int dw = -1; dw <= 1; ++dw) {
                int x = w + dw;
                if (x < 0 || x >= WW) continue;
                int tap = (dd + 1) * 9 + (dh + 1) * 3 + (dw + 1);
                const float4* xp =
                    (const float4*)(X + (((size_t)z * HH + y) * WW + x) * GG);
                const float4* wr = (const float4*)(WfT + tap * GG);
#pragma unroll
                for (int q = 0; q < GG / 4; ++q) {
                    float4 xv = xp[q];
                    float4 wv = wr[q];
                    acc += xv.x * wv.x + xv.y * wv.y + xv.z * wv.z + xv.w * wv.w;
                }
            }
        }
    }
    Y[s] = acc;
}

// ---------------------------------------------------------------------------
// Launch
// ---------------------------------------------------------------------------
extern "C" void kernel_launch(void* const* d_in, const int* in_sizes, int n_in,
                              void* d_out, int out_size, void* d_ws, size_t ws_size,
                              hipStream_t stream) {
    const float* left  = (const float*)d_in[0];
    const float* right = (const float*)d_in[1];
    const float* w0 = (const float*)d_in[2];
    const float* b0 = (const float*)d_in[3];
    const float* w1 = (const float*)d_in[4];
    const float* b1 = (const float*)d_in[5];
    const float* w2 = (const float*)d_in[6];
    const float* b2 = (const float*)d_in[7];
    const float* w3 = (const float*)d_in[8];
    const float* b3 = (const float*)d_in[9];
    const float* wf = (const float*)d_in[10];
    const float* bf = (const float*)d_in[11];

    float* ws   = (float*)d_ws;
    float* volA = ws;                          // 12,582,912 floats
    float* volB = volA + VOL_ELEMS;            // 12,582,912 floats
    float* wT0  = volB + VOL_ELEMS;            // 27648 floats each
    float* wT1  = wT0 + 27648;
    float* wT2  = wT1 + 27648;
    float* wT3  = wT2 + 27648;
    float* wfT  = wT3 + 27648;                 // 864 floats
    // total ws use: ~101 MB

    // weight transposes (tiny)
    transpose_w_kernel<<<(27648 + 255) / 256, 256, 0, stream>>>(w0, wT0, HID, GG);
    transpose_w_kernel<<<(27648 + 255) / 256, 256, 0, stream>>>(w1, wT1, HID, HID);
    transpose_w_kernel<<<(27648 + 255) / 256, 256, 0, stream>>>(w2, wT2, HID, HID);
    transpose_w_kernel<<<(27648 + 255) / 256, 256, 0, stream>>>(w3, wT3, HID, HID);
    transpose_w_kernel<<<(864 + 255) / 256, 256, 0, stream>>>(wf, wfT, 1, GG);

    // cost volume (channels-last)
    build_vol_kernel<<<dim3(HH, GG), WW, 0, stream>>>(left, right, volA);

    // aggregation
    int blocks = (SPATIAL + 255) / 256;
    conv3d_lrelu_kernel<<<blocks, 256, 0, stream>>>(volA, wT0, b0, volB, 1);
    conv3d_lrelu_kernel<<<blocks, 256, 0, stream>>>(volB, wT1, b1, volA, 1);
    conv3d_lrelu_kernel<<<blocks, 256, 0, stream>>>(volA, wT2, b2, volB, 1);
    conv3d_lrelu_kernel<<<blocks, 256, 0, stream>>>(volB, wT3, b3, volA, 1);
    conv3d_final_kernel<<<blocks, 256, 0, stream>>>(volA, wfT, bf, (float*)d_out);
}

// Round 2
// 543.225 us; speedup vs baseline: 4.9620x; 4.9620x over previous
//
#include <hip/hip_runtime.h>
#include <hip/hip_bf16.h>

// Problem constants
#define HH 64
#define WW 128
#define DD 48
#define GG 32
#define CG 8
#define HID 32
// Padded volume: [50][66][130][32] channels-last bf16
#define PD 50
#define PH 66
#define PW 130
#define PVOL ((size_t)PD * PH * PW * 32)   // 13,728,000 elems

typedef __hip_bfloat16 bf16;
typedef __attribute__((ext_vector_type(8))) short short8;
typedef __attribute__((ext_vector_type(4))) float f32x4;

// ---------------------------------------------------------------------------
// Weight conversion: fp32 [O=32][I=32][27] -> bf16 [tap][co][ci]
// ---------------------------------------------------------------------------
__global__ void convert_w_mid_kernel(const float* __restrict__ src,
                                     bf16* __restrict__ dst) {
    int tid = blockIdx.x * 256 + threadIdx.x;
    if (tid >= 27 * 32 * 32) return;
    int tap = tid >> 10;
    int co  = (tid >> 5) & 31;
    int ci  = tid & 31;
    dst[tid] = __float2bfloat16(src[(co * 32 + ci) * 27 + tap]);
}

// final: fp32 [1][32][27] -> bf16 [tap][co<16][ci], col 0 real, cols 1..15 zero
__global__ void convert_w_final_kernel(const float* __restrict__ src,
                                       bf16* __restrict__ dst) {
    int tid = blockIdx.x * 256 + threadIdx.x;
    if (tid >= 27 * 16 * 32) return;
    int tap = tid >> 9;
    int co  = (tid >> 5) & 15;
    int ci  = tid & 31;
    dst[tid] = (co == 0) ? __float2bfloat16(src[ci * 27 + tap])
                         : __float2bfloat16(0.f);
}

// ---------------------------------------------------------------------------
// Cost volume -> padded bf16 channels-last.
// Thread = (g in 0..31, wq in 0..7); block covers 8 w; grid (W/8, H).
// Stores coalesced along g (fastest dim of the padded layout).
// ---------------------------------------------------------------------------
__global__ __launch_bounds__(256) void build_vol_kernel(
    const float* __restrict__ L, const float* __restrict__ R,
    bf16* __restrict__ vol) {
    int g  = threadIdx.x & 31;
    int wq = threadIdx.x >> 5;
    int w  = blockIdx.x * 8 + wq;
    int h  = blockIdx.y;

    float lv[CG];
    const float* Lp = L + ((size_t)(g * CG) * HH + h) * WW + w;
    const float* Rp = R + ((size_t)(g * CG) * HH + h) * WW;
#pragma unroll
    for (int cc = 0; cc < CG; ++cc) lv[cc] = Lp[(size_t)cc * HH * WW];

    bf16* outp = vol + (((size_t)(h + 1)) * PW + (w + 1)) * 32 + g;
    int dmax = (w + 1 < DD) ? (w + 1) : DD;
    for (int d = 0; d < DD; ++d) {
        float s = 0.f;
        if (d < dmax) {
            int x = w - d;
#pragma unroll
            for (int cc = 0; cc < CG; ++cc)
                s += lv[cc] * Rp[(size_t)cc * HH * WW + x];
            s *= 0.125f;
        }
        outp[((size_t)(d + 1)) * PH * PW * 32] = __float2bfloat16(s);
    }
}

// ---------------------------------------------------------------------------
// Mid conv layer via MFMA: X[pad][32] bf16 -> Y[pad][32] bf16, lrelu(0.2).
// Block = 4 waves; block -> (d, h pair); wave -> one 64-wide w strip of one h.
// Per wave: 4 M-tiles (16 w each) x 2 N-tiles (co 0-15,16-31), K = 27 taps x 32ci.
// A-frag: lane l loads X[point(l&15)][ci (l>>4)*8..+7] = 16B contiguous global.
// B-frag: lane l loads Wb[tap][co l&15][ci (l>>4)*8..+7] = 16B (L1-cached).
// ---------------------------------------------------------------------------
__global__ __launch_bounds__(256) void conv_mid_kernel(
    const bf16* __restrict__ X, const bf16* __restrict__ Wb,
    const float* __restrict__ bias, bf16* __restrict__ Y) {
    int d    = blockIdx.x >> 5;
    int hp   = blockIdx.x & 31;
    int wave = threadIdx.x >> 6;
    int lane = threadIdx.x & 63;
    int h    = hp * 2 + (wave >> 1);
    int w0   = (wave & 1) * 64;
    int arow = lane & 15;
    int kg   = lane >> 4;

    f32x4 acc[4][2] = {};
    const short8* Wv = (const short8*)Wb;

#pragma unroll
    for (int dz = 0; dz < 3; ++dz)
#pragma unroll
        for (int dy = 0; dy < 3; ++dy) {
            const short8* Xp =
                (const short8*)X + ((size_t)((d + dz) * PH + (h + dy)) * PW) * 4;
#pragma unroll
            for (int dx = 0; dx < 3; ++dx) {
                int tap = dz * 9 + dy * 3 + dx;
                short8 b0 = Wv[tap * 128 + arow * 4 + kg];
                short8 b1 = Wv[tap * 128 + 64 + arow * 4 + kg];
#pragma unroll
                for (int t = 0; t < 4; ++t) {
                    short8 a = Xp[(w0 + 16 * t + arow + dx) * 4 + kg];
                    acc[t][0] = __builtin_amdgcn_mfma_f32_16x16x32_bf16(
                        a, b0, acc[t][0], 0, 0, 0);
                    acc[t][1] = __builtin_amdgcn_mfma_f32_16x16x32_bf16(
                        a, b1, acc[t][1], 0, 0, 0);
                }
            }
        }

    // Epilogue: D mapping col=lane&15, row=(lane>>4)*4+reg
    float bv0 = bias[arow];
    float bv1 = bias[arow + 16];
    int rowD = kg * 4;
    bf16* Yp = Y + (((size_t)(d + 1) * PH + (h + 1)) * PW + 1) * 32;
#pragma unroll
    for (int t = 0; t < 4; ++t)
#pragma unroll
        for (int r = 0; r < 4; ++r) {
            int wout = w0 + 16 * t + rowD + r;
            float v0 = acc[t][0][r] + bv0;
            float v1 = acc[t][1][r] + bv1;
            v0 = fmaxf(v0, 0.f) + 0.2f * fminf(v0, 0.f);
            v1 = fmaxf(v1, 0.f) + 0.2f * fminf(v1, 0.f);
            Yp[(size_t)wout * 32 + arow]      = __float2bfloat16(v0);
            Yp[(size_t)wout * 32 + arow + 16] = __float2bfloat16(v1);
        }
}

// ---------------------------------------------------------------------------
// Final conv (32ch -> 1) via MFMA (N-tile of 16, only col 0 real). fp32 out.
// ---------------------------------------------------------------------------
__global__ __launch_bounds__(256) void conv_final_kernel(
    const bf16* __restrict__ X, const bf16* __restrict__ Wb,
    const float* __restrict__ bias, float* __restrict__ out) {
    int d    = blockIdx.x >> 5;
    int hp   = blockIdx.x & 31;
    int wave = threadIdx.x >> 6;
    int lane = threadIdx.x & 63;
    int h    = hp * 2 + (wave >> 1);
    int w0   = (wave & 1) * 64;
    int arow = lane & 15;
    int kg   = lane >> 4;

    f32x4 acc[4] = {};
    const short8* Wv = (const short8*)Wb;

#pragma unroll
    for (int dz = 0; dz < 3; ++dz)
#pragma unroll
        for (int dy = 0; dy < 3; ++dy) {
            const short8* Xp =
                (const short8*)X + ((size_t)((d + dz) * PH + (h + dy)) * PW) * 4;
#pragma unroll
            for (int dx = 0; dx < 3; ++dx) {
                int tap = dz * 9 + dy * 3 + dx;
                short8 b = Wv[tap * 64 + arow * 4 + kg];
#pragma unroll
                for (int t = 0; t < 4; ++t) {
                    short8 a = Xp[(w0 + 16 * t + arow + dx) * 4 + kg];
                    acc[t] = __builtin_amdgcn_mfma_f32_16x16x32_bf16(
                        a, b, acc[t], 0, 0, 0);
                }
            }
        }

    if (arow == 0) {
        float bv = bias[0];
        int rowD = kg * 4;
#pragma unroll
        for (int t = 0; t < 4; ++t)
#pragma unroll
            for (int r = 0; r < 4; ++r)
                out[((size_t)d * HH + h) * WW + w0 + 16 * t + rowD + r] =
                    acc[t][r] + bv;
    }
}

// ---------------------------------------------------------------------------
// Launch
// ---------------------------------------------------------------------------
extern "C" void kernel_launch(void* const* d_in, const int* in_sizes, int n_in,
                              void* d_out, int out_size, void* d_ws, size_t ws_size,
                              hipStream_t stream) {
    const float* left  = (const float*)d_in[0];
    const float* right = (const float*)d_in[1];
    const float* w0 = (const float*)d_in[2];
    const float* b0 = (const float*)d_in[3];
    const float* w1 = (const float*)d_in[4];
    const float* b1 = (const float*)d_in[5];
    const float* w2 = (const float*)d_in[6];
    const float* b2 = (const float*)d_in[7];
    const float* w3 = (const float*)d_in[8];
    const float* b3 = (const float*)d_in[9];
    const float* wf = (const float*)d_in[10];
    const float* bf = (const float*)d_in[11];

    bf16* volA = (bf16*)d_ws;
    bf16* volB = volA + PVOL;
    bf16* wb0  = volB + PVOL;
    bf16* wb1  = wb0 + 27648;
    bf16* wb2  = wb1 + 27648;
    bf16* wb3  = wb2 + 27648;
    bf16* wbf  = wb3 + 27648;   // 13824 elems
    // total ~55.2 MB of ws

    // zero padding (interiors get overwritten every call)
    hipMemsetAsync(volA, 0, PVOL * sizeof(bf16), stream);
    hipMemsetAsync(volB, 0, PVOL * sizeof(bf16), stream);

    convert_w_mid_kernel<<<108, 256, 0, stream>>>(w0, wb0);
    convert_w_mid_kernel<<<108, 256, 0, stream>>>(w1, wb1);
    convert_w_mid_kernel<<<108, 256, 0, stream>>>(w2, wb2);
    convert_w_mid_kernel<<<108, 256, 0, stream>>>(w3, wb3);
    convert_w_final_kernel<<<54, 256, 0, stream>>>(wf, wbf);

    build_vol_kernel<<<dim3(WW / 8, HH), 256, 0, stream>>>(left, right, volA);

    int grid = DD * (HH / 2);   // 1536
    conv_mid_kernel<<<grid, 256, 0, stream>>>(volA, wb0, b0, volB);
    conv_mid_kernel<<<grid, 256, 0, stream>>>(volB, wb1, b1, volA);
    conv_mid_kernel<<<grid, 256, 0, stream>>>(volA, wb2, b2, volB);
    conv_mid_kernel<<<grid, 256, 0, stream>>>(volB, wb3, b3, volA);
    conv_final_kernel<<<grid, 256, 0, stream>>>(volA, wbf, bf, (float*)d_out);
}

// Round 3
// 376.883 us; speedup vs baseline: 7.1520x; 1.4414x over previous
//
#include <hip/hip_runtime.h>
#include <hip/hip_bf16.h>

// Problem constants
#define HH 64
#define WW 128
#define DD 48
#define GG 32
#define CG 8
#define HID 32
// Padded volume: [50][66][130][32] channels-last bf16
#define PD 50
#define PH 66
#define PW 130
#define PVOL ((size_t)PD * PH * PW * 32)   // 13,728,000 elems
#define FEAT ((size_t)HH * WW * 256)       // 2,097,152 elems

typedef __hip_bfloat16 bf16;
typedef __attribute__((ext_vector_type(8))) short short8;
typedef __attribute__((ext_vector_type(4))) float f32x4;

// ---------------------------------------------------------------------------
// Feature transpose: [256][64][128] f32 -> [64][128][256] f32 (channels-last)
// Block: 256 threads, handles (h, 32-wide w tile). LDS tile [32][257] f32.
// ---------------------------------------------------------------------------
__global__ __launch_bounds__(256) void transpose_feat_kernel(
    const float* __restrict__ src, float* __restrict__ dst) {
    __shared__ float tile[32][257];
    int tid = threadIdx.x;
    int w0  = blockIdx.x * 32;
    int h   = blockIdx.y;

#pragma unroll
    for (int it = 0; it < 32; ++it) {
        int c = it * 8 + (tid >> 5);
        tile[tid & 31][c] =
            src[(size_t)c * (HH * WW) + h * WW + w0 + (tid & 31)];
    }
    __syncthreads();

    int c_l = tid & 63, wg = tid >> 6;
#pragma unroll
    for (int it = 0; it < 8; ++it) {
        int w_i = it * 4 + wg;
        float* dp = dst + ((size_t)h * WW + w0 + w_i) * 256;
#pragma unroll
        for (int cc = 0; cc < 256; cc += 64)
            dp[cc + c_l] = tile[w_i][cc + c_l];
    }
}

// ---------------------------------------------------------------------------
// Weight conversion: fp32 [O=32][I=32][27] -> bf16 [tap][co][ci]
// ---------------------------------------------------------------------------
__global__ void convert_w_mid_kernel(const float* __restrict__ src,
                                     bf16* __restrict__ dst) {
    int tid = blockIdx.x * 256 + threadIdx.x;
    if (tid >= 27 * 32 * 32) return;
    int tap = tid >> 10;
    int co  = (tid >> 5) & 31;
    int ci  = tid & 31;
    dst[tid] = __float2bfloat16(src[(co * 32 + ci) * 27 + tap]);
}

// final: fp32 [1][32][27] -> bf16 [tap][co<16][ci], col 0 real, cols 1..15 zero
__global__ void convert_w_final_kernel(const float* __restrict__ src,
                                       bf16* __restrict__ dst) {
    int tid = blockIdx.x * 256 + threadIdx.x;
    if (tid >= 27 * 16 * 32) return;
    int tap = tid >> 9;
    int co  = (tid >> 5) & 15;
    int ci  = tid & 31;
    dst[tid] = (co == 0) ? __float2bfloat16(src[ci * 27 + tap])
                         : __float2bfloat16(0.f);
}

// ---------------------------------------------------------------------------
// Cost volume from channels-last features. Thread = (g, wq); fully coalesced:
// lane g reads L/R[h][w][g*8..+7] (32B), writes vol[...][g] (2B, g fastest).
// ---------------------------------------------------------------------------
__global__ __launch_bounds__(256) void build_vol_kernel(
    const float* __restrict__ Lt, const float* __restrict__ Rt,
    bf16* __restrict__ vol) {
    int g  = threadIdx.x & 31;
    int wq = threadIdx.x >> 5;
    int w  = blockIdx.x * 8 + wq;
    int h  = blockIdx.y;

    const float4* lp = (const float4*)(Lt + ((size_t)h * WW + w) * 256 + g * 8);
    float4 l0 = lp[0], l1 = lp[1];
    const float* Rrow = Rt + (size_t)h * WW * 256;

    bf16* outp = vol + (((size_t)(h + 1)) * PW + (w + 1)) * 32 + g;
    for (int d = 0; d < DD; ++d) {
        int x = w - d;
        float s = 0.f;
        if (x >= 0) {
            const float4* rp = (const float4*)(Rrow + (size_t)x * 256 + g * 8);
            float4 r0 = rp[0], r1 = rp[1];
            s = l0.x * r0.x + l0.y * r0.y + l0.z * r0.z + l0.w * r0.w +
                l1.x * r1.x + l1.y * r1.y + l1.z * r1.z + l1.w * r1.w;
            s *= 0.125f;
        }
        outp[((size_t)(d + 1)) * PH * PW * 32] = __float2bfloat16(s);
    }
}

// ---------------------------------------------------------------------------
// Mid conv layer via MFMA: X[pad][32] bf16 -> Y[pad][32] bf16, lrelu(0.2).
// ---------------------------------------------------------------------------
__global__ __launch_bounds__(256) void conv_mid_kernel(
    const bf16* __restrict__ X, const bf16* __restrict__ Wb,
    const float* __restrict__ bias, bf16* __restrict__ Y) {
    int d    = blockIdx.x >> 5;
    int hp   = blockIdx.x & 31;
    int wave = threadIdx.x >> 6;
    int lane = threadIdx.x & 63;
    int h    = hp * 2 + (wave >> 1);
    int w0   = (wave & 1) * 64;
    int arow = lane & 15;
    int kg   = lane >> 4;

    f32x4 acc[4][2] = {};
    const short8* Wv = (const short8*)Wb;

#pragma unroll
    for (int dz = 0; dz < 3; ++dz)
#pragma unroll
        for (int dy = 0; dy < 3; ++dy) {
            const short8* Xp =
                (const short8*)X + ((size_t)((d + dz) * PH + (h + dy)) * PW) * 4;
#pragma unroll
            for (int dx = 0; dx < 3; ++dx) {
                int tap = dz * 9 + dy * 3 + dx;
                short8 b0 = Wv[tap * 128 + arow * 4 + kg];
                short8 b1 = Wv[tap * 128 + 64 + arow * 4 + kg];
#pragma unroll
                for (int t = 0; t < 4; ++t) {
                    short8 a = Xp[(w0 + 16 * t + arow + dx) * 4 + kg];
                    acc[t][0] = __builtin_amdgcn_mfma_f32_16x16x32_bf16(
                        a, b0, acc[t][0], 0, 0, 0);
                    acc[t][1] = __builtin_amdgcn_mfma_f32_16x16x32_bf16(
                        a, b1, acc[t][1], 0, 0, 0);
                }
            }
        }

    float bv0 = bias[arow];
    float bv1 = bias[arow + 16];
    int rowD = kg * 4;
    bf16* Yp = Y + (((size_t)(d + 1) * PH + (h + 1)) * PW + 1) * 32;
#pragma unroll
    for (int t = 0; t < 4; ++t)
#pragma unroll
        for (int r = 0; r < 4; ++r) {
            int wout = w0 + 16 * t + rowD + r;
            float v0 = acc[t][0][r] + bv0;
            float v1 = acc[t][1][r] + bv1;
            v0 = fmaxf(v0, 0.f) + 0.2f * fminf(v0, 0.f);
            v1 = fmaxf(v1, 0.f) + 0.2f * fminf(v1, 0.f);
            Yp[(size_t)wout * 32 + arow]      = __float2bfloat16(v0);
            Yp[(size_t)wout * 32 + arow + 16] = __float2bfloat16(v1);
        }
}

// ---------------------------------------------------------------------------
// Final conv (32ch -> 1) via MFMA. fp32 out.
// ---------------------------------------------------------------------------
__global__ __launch_bounds__(256) void conv_final_kernel(
    const bf16* __restrict__ X, const bf16* __restrict__ Wb,
    const float* __restrict__ bias, float* __restrict__ out) {
    int d    = blockIdx.x >> 5;
    int hp   = blockIdx.x & 31;
    int wave = threadIdx.x >> 6;
    int lane = threadIdx.x & 63;
    int h    = hp * 2 + (wave >> 1);
    int w0   = (wave & 1) * 64;
    int arow = lane & 15;
    int kg   = lane >> 4;

    f32x4 acc[4] = {};
    const short8* Wv = (const short8*)Wb;

#pragma unroll
    for (int dz = 0; dz < 3; ++dz)
#pragma unroll
        for (int dy = 0; dy < 3; ++dy) {
            const short8* Xp =
                (const short8*)X + ((size_t)((d + dz) * PH + (h + dy)) * PW) * 4;
#pragma unroll
            for (int dx = 0; dx < 3; ++dx) {
                int tap = dz * 9 + dy * 3 + dx;
                short8 b = Wv[tap * 64 + arow * 4 + kg];
#pragma unroll
                for (int t = 0; t < 4; ++t) {
                    short8 a = Xp[(w0 + 16 * t + arow + dx) * 4 + kg];
                    acc[t] = __builtin_amdgcn_mfma_f32_16x16x32_bf16(
                        a, b, acc[t], 0, 0, 0);
                }
            }
        }

    if (arow == 0) {
        float bv = bias[0];
        int rowD = kg * 4;
#pragma unroll
        for (int t = 0; t < 4; ++t)
#pragma unroll
            for (int r = 0; r < 4; ++r)
                out[((size_t)d * HH + h) * WW + w0 + 16 * t + rowD + r] =
                    acc[t][r] + bv;
    }
}

// ---------------------------------------------------------------------------
// Launch
// ---------------------------------------------------------------------------
extern "C" void kernel_launch(void* const* d_in, const int* in_sizes, int n_in,
                              void* d_out, int out_size, void* d_ws, size_t ws_size,
                              hipStream_t stream) {
    const float* left  = (const float*)d_in[0];
    const float* right = (const float*)d_in[1];
    const float* w0 = (const float*)d_in[2];
    const float* b0 = (const float*)d_in[3];
    const float* w1 = (const float*)d_in[4];
    const float* b1 = (const float*)d_in[5];
    const float* w2 = (const float*)d_in[6];
    const float* b2 = (const float*)d_in[7];
    const float* w3 = (const float*)d_in[8];
    const float* b3 = (const float*)d_in[9];
    const float* wf = (const float*)d_in[10];
    const float* bf = (const float*)d_in[11];

    bf16* volA = (bf16*)d_ws;
    bf16* volB = volA + PVOL;
    bf16* wb0  = volB + PVOL;
    bf16* wb1  = wb0 + 27648;
    bf16* wb2  = wb1 + 27648;
    bf16* wb3  = wb2 + 27648;
    bf16* wbf  = wb3 + 27648;   // 13824 elems
    float* Lt  = (float*)(wbf + 13824 + 32);  // aligned-ish; 2,097,152 f32 each
    float* Rt  = Lt + FEAT;
    // total ws use: ~71 MB

    // zero padding (interiors get overwritten every call)
    hipMemsetAsync(volA, 0, PVOL * sizeof(bf16), stream);
    hipMemsetAsync(volB, 0, PVOL * sizeof(bf16), stream);

    convert_w_mid_kernel<<<108, 256, 0, stream>>>(w0, wb0);
    convert_w_mid_kernel<<<108, 256, 0, stream>>>(w1, wb1);
    convert_w_mid_kernel<<<108, 256, 0, stream>>>(w2, wb2);
    convert_w_mid_kernel<<<108, 256, 0, stream>>>(w3, wb3);
    convert_w_final_kernel<<<54, 256, 0, stream>>>(wf, wbf);

    transpose_feat_kernel<<<dim3(WW / 32, HH), 256, 0, stream>>>(left, Lt);
    transpose_feat_kernel<<<dim3(WW / 32, HH), 256, 0, stream>>>(right, Rt);

    build_vol_kernel<<<dim3(WW / 8, HH), 256, 0, stream>>>(Lt, Rt, volA);

    int grid = DD * (HH / 2);   // 1536
    conv_mid_kernel<<<grid, 256, 0, stream>>>(volA, wb0, b0, volB);
    conv_mid_kernel<<<grid, 256, 0, stream>>>(volB, wb1, b1, volA);
    conv_mid_kernel<<<grid, 256, 0, stream>>>(volA, wb2, b2, volB);
    conv_mid_kernel<<<grid, 256, 0, stream>>>(volB, wb3, b3, volA);
    conv_final_kernel<<<grid, 256, 0, stream>>>(volA, wbf, bf, (float*)d_out);
}

// Round 4
// 282.360 us; speedup vs baseline: 9.5462x; 1.3348x over previous
//
#include <hip/hip_runtime.h>
#include <hip/hip_bf16.h>

// Problem constants
#define HH 64
#define WW 128
#define DD 48
#define GG 32
#define CG 8
#define HID 32
// Padded volume: [50][66][130][32] channels-last bf16
#define PD 50
#define PH 66
#define PW 130
#define PVOL ((size_t)PD * PH * PW * 32)   // 13,728,000 elems
#define FEAT ((size_t)HH * WW * 256)       // 2,097,152 elems
#define ROWE 4160                          // elems per padded row (PW*32)
#define ROWB 8320                          // bytes per row
#define CHUNKB 24960                       // 3 contiguous rows (dy) in bytes
#define LDSE (9 * 4160)                    // staged 9 rows, elems

typedef __hip_bfloat16 bf16;
typedef __attribute__((ext_vector_type(8))) short short8;
typedef __attribute__((ext_vector_type(4))) float f32x4;

__device__ __forceinline__ void gload_lds16(const bf16* g, bf16* l) {
    __builtin_amdgcn_global_load_lds(
        (const __attribute__((address_space(1))) unsigned int*)g,
        (__attribute__((address_space(3))) unsigned int*)l, 16, 0, 0);
}

// ---------------------------------------------------------------------------
// Border zeroing of both padded volumes (replaces 55 MB of memset with 4.6 MB)
// ---------------------------------------------------------------------------
#define BORDER_ELEMS 1145088
__global__ __launch_bounds__(256) void border_zero_kernel(bf16* __restrict__ volA,
                                                          bf16* __restrict__ volB) {
    size_t tid = (size_t)blockIdx.x * 256 + threadIdx.x;
    if (tid >= 2 * (size_t)BORDER_ELEMS) return;
    bf16* vol = (tid >= BORDER_ELEMS) ? volB : volA;
    size_t i = (tid >= BORDER_ELEMS) ? tid - BORDER_ELEMS : tid;
    size_t addr;
    if (i < 549120) {                       // d-slices 0 and 49, full
        int dsl = (i < 274560) ? 0 : 49;
        size_t rem = i % 274560;
        addr = (size_t)dsl * PH * PW * 32 + rem;
    } else if (i < 948480) {                // h rows 0 and 65
        size_t j = i - 549120;
        int dd = (int)(j / ROWB);           // ROWB elems? careful: 8320 elems here
        size_t rr = j % ROWB;
        int hh2 = (rr < ROWE) ? 0 : 65;
        size_t off = rr % ROWE;
        addr = ((size_t)(dd + 1) * PH + hh2) * PW * 32 + off;
    } else {                                // w cols 0 and 129
        size_t j = i - 948480;
        int dd = (int)(j / 4096);
        size_t rr = j % 4096;
        int hh2 = (int)(rr / 64) + 1;
        int e = (int)(rr & 63);
        int wcol = (e < 32) ? 0 : 129;
        addr = (((size_t)(dd + 1) * PH + hh2) * PW + wcol) * 32 + (e & 31);
    }
    vol[addr] = __float2bfloat16(0.f);
}

// ---------------------------------------------------------------------------
// Feature transpose: [256][64][128] f32 -> [64][128][256] f32
// ---------------------------------------------------------------------------
__global__ __launch_bounds__(256) void transpose_feat_kernel(
    const float* __restrict__ src, float* __restrict__ dst) {
    __shared__ float tile[32][257];
    int tid = threadIdx.x;
    int w0  = blockIdx.x * 32;
    int h   = blockIdx.y;

#pragma unroll
    for (int it = 0; it < 32; ++it) {
        int c = it * 8 + (tid >> 5);
        tile[tid & 31][c] =
            src[(size_t)c * (HH * WW) + h * WW + w0 + (tid & 31)];
    }
    __syncthreads();

    int c_l = tid & 63, wg = tid >> 6;
#pragma unroll
    for (int it = 0; it < 8; ++it) {
        int w_i = it * 4 + wg;
        float* dp = dst + ((size_t)h * WW + w0 + w_i) * 256;
#pragma unroll
        for (int cc = 0; cc < 256; cc += 64)
            dp[cc + c_l] = tile[w_i][cc + c_l];
    }
}

// ---------------------------------------------------------------------------
// Weight conversion: fp32 [O=32][I=32][27] -> bf16 [tap][co][ci]
// ---------------------------------------------------------------------------
__global__ void convert_w_mid_kernel(const float* __restrict__ src,
                                     bf16* __restrict__ dst) {
    int tid = blockIdx.x * 256 + threadIdx.x;
    if (tid >= 27 * 32 * 32) return;
    int tap = tid >> 10;
    int co  = (tid >> 5) & 31;
    int ci  = tid & 31;
    dst[tid] = __float2bfloat16(src[(co * 32 + ci) * 27 + tap]);
}

__global__ void convert_w_final_kernel(const float* __restrict__ src,
                                       bf16* __restrict__ dst) {
    int tid = blockIdx.x * 256 + threadIdx.x;
    if (tid >= 27 * 16 * 32) return;
    int tap = tid >> 9;
    int co  = (tid >> 5) & 15;
    int ci  = tid & 31;
    dst[tid] = (co == 0) ? __float2bfloat16(src[ci * 27 + tap])
                         : __float2bfloat16(0.f);
}

// ---------------------------------------------------------------------------
// Cost volume from channels-last features (coalesced).
// ---------------------------------------------------------------------------
__global__ __launch_bounds__(256) void build_vol_kernel(
    const float* __restrict__ Lt, const float* __restrict__ Rt,
    bf16* __restrict__ vol) {
    int g  = threadIdx.x & 31;
    int wq = threadIdx.x >> 5;
    int w  = blockIdx.x * 8 + wq;
    int h  = blockIdx.y;

    const float4* lp = (const float4*)(Lt + ((size_t)h * WW + w) * 256 + g * 8);
    float4 l0 = lp[0], l1 = lp[1];
    const float* Rrow = Rt + (size_t)h * WW * 256;

    bf16* outp = vol + (((size_t)(h + 1)) * PW + (w + 1)) * 32 + g;
    for (int d = 0; d < DD; ++d) {
        int x = w - d;
        float s = 0.f;
        if (x >= 0) {
            const float4* rp = (const float4*)(Rrow + (size_t)x * 256 + g * 8);
            float4 r0 = rp[0], r1 = rp[1];
            s = l0.x * r0.x + l0.y * r0.y + l0.z * r0.z + l0.w * r0.w +
                l1.x * r1.x + l1.y * r1.y + l1.z * r1.z + l1.w * r1.w;
            s *= 0.125f;
        }
        outp[((size_t)(d + 1)) * PH * PW * 32] = __float2bfloat16(s);
    }
}

// ---------------------------------------------------------------------------
// Mid conv via MFMA with LDS-staged input rows.
// Block = (d,h) [XCD-swizzled], 4 waves by w-quarter (32 w each), N full (32).
// Stage: 9 rows [dz 3][dy 3] x 8320 B = 74880 B via global_load_lds w16.
// ---------------------------------------------------------------------------
__global__ __launch_bounds__(256) void conv_mid_kernel(
    const bf16* __restrict__ X, const bf16* __restrict__ Wb,
    const float* __restrict__ bias, bf16* __restrict__ Y) {
    __shared__ bf16 lds[LDSE];
    int id  = blockIdx.x;
    int swz = (id & 7) * 384 + (id >> 3);   // bijective: 3072 = 8*384
    int d = swz >> 6;
    int h = swz & 63;
    int wave = threadIdx.x >> 6;
    int lane = threadIdx.x & 63;

    // ---- stage: per dz one contiguous 24960 B chunk; wave handles 6240 B
    {
        int wbase = wave * 6240;
#pragma unroll
        for (int dz = 0; dz < 3; ++dz) {
            const bf16* src =
                (const bf16*)((const char*)(X + ((size_t)(d + dz) * PH + h) * ROWE) + wbase);
            bf16* dst = (bf16*)((char*)lds + dz * CHUNKB + wbase);
#pragma unroll
            for (int it = 0; it < 6; ++it)
                gload_lds16((const bf16*)((const char*)src + it * 1024 + lane * 16),
                            (bf16*)((char*)dst + it * 1024));
            if (lane < 6)
                gload_lds16((const bf16*)((const char*)src + 6144 + lane * 16),
                            (bf16*)((char*)dst + 6144));
        }
    }
    __syncthreads();

    int w0   = wave * 32;
    int arow = lane & 15;
    int kg   = lane >> 4;

    f32x4 acc[2][2] = {};
    const short8* Wv = (const short8*)Wb;

#pragma unroll
    for (int dz = 0; dz < 3; ++dz)
#pragma unroll
        for (int dy = 0; dy < 3; ++dy) {
            const short8* Ar = (const short8*)(lds + (size_t)(dz * 3 + dy) * ROWE);
#pragma unroll
            for (int dx = 0; dx < 3; ++dx) {
                int tap = dz * 9 + dy * 3 + dx;
                short8 b0 = Wv[tap * 128 + arow * 4 + kg];
                short8 b1 = Wv[tap * 128 + 64 + arow * 4 + kg];
#pragma unroll
                for (int t = 0; t < 2; ++t) {
                    short8 a = Ar[(w0 + 16 * t + arow + dx) * 4 + kg];
                    acc[t][0] = __builtin_amdgcn_mfma_f32_16x16x32_bf16(
                        a, b0, acc[t][0], 0, 0, 0);
                    acc[t][1] = __builtin_amdgcn_mfma_f32_16x16x32_bf16(
                        a, b1, acc[t][1], 0, 0, 0);
                }
            }
        }

    float bv0 = bias[arow];
    float bv1 = bias[arow + 16];
    int rowD = kg * 4;
    bf16* Yp = Y + (((size_t)(d + 1) * PH + (h + 1)) * PW + 1) * 32;
#pragma unroll
    for (int t = 0; t < 2; ++t)
#pragma unroll
        for (int r = 0; r < 4; ++r) {
            int wout = w0 + 16 * t + rowD + r;
            float v0 = acc[t][0][r] + bv0;
            float v1 = acc[t][1][r] + bv1;
            v0 = fmaxf(v0, 0.f) + 0.2f * fminf(v0, 0.f);
            v1 = fmaxf(v1, 0.f) + 0.2f * fminf(v1, 0.f);
            Yp[(size_t)wout * 32 + arow]      = __float2bfloat16(v0);
            Yp[(size_t)wout * 32 + arow + 16] = __float2bfloat16(v1);
        }
}

// ---------------------------------------------------------------------------
// Final conv (32ch -> 1) via MFMA with LDS staging. fp32 out.
// ---------------------------------------------------------------------------
__global__ __launch_bounds__(256) void conv_final_kernel(
    const bf16* __restrict__ X, const bf16* __restrict__ Wb,
    const float* __restrict__ bias, float* __restrict__ out) {
    __shared__ bf16 lds[LDSE];
    int id  = blockIdx.x;
    int swz = (id & 7) * 384 + (id >> 3);
    int d = swz >> 6;
    int h = swz & 63;
    int wave = threadIdx.x >> 6;
    int lane = threadIdx.x & 63;

    {
        int wbase = wave * 6240;
#pragma unroll
        for (int dz = 0; dz < 3; ++dz) {
            const bf16* src =
                (const bf16*)((const char*)(X + ((size_t)(d + dz) * PH + h) * ROWE) + wbase);
            bf16* dst = (bf16*)((char*)lds + dz * CHUNKB + wbase);
#pragma unroll
            for (int it = 0; it < 6; ++it)
                gload_lds16((const bf16*)((const char*)src + it * 1024 + lane * 16),
                            (bf16*)((char*)dst + it * 1024));
            if (lane < 6)
                gload_lds16((const bf16*)((const char*)src + 6144 + lane * 16),
                            (bf16*)((char*)dst + 6144));
        }
    }
    __syncthreads();

    int w0   = wave * 32;
    int arow = lane & 15;
    int kg   = lane >> 4;

    f32x4 acc[2] = {};
    const short8* Wv = (const short8*)Wb;

#pragma unroll
    for (int dz = 0; dz < 3; ++dz)
#pragma unroll
        for (int dy = 0; dy < 3; ++dy) {
            const short8* Ar = (const short8*)(lds + (size_t)(dz * 3 + dy) * ROWE);
#pragma unroll
            for (int dx = 0; dx < 3; ++dx) {
                int tap = dz * 9 + dy * 3 + dx;
                short8 b = Wv[tap * 64 + arow * 4 + kg];
#pragma unroll
                for (int t = 0; t < 2; ++t) {
                    short8 a = Ar[(w0 + 16 * t + arow + dx) * 4 + kg];
                    acc[t] = __builtin_amdgcn_mfma_f32_16x16x32_bf16(
                        a, b, acc[t], 0, 0, 0);
                }
            }
        }

    if (arow == 0) {
        float bv = bias[0];
        int rowD = kg * 4;
#pragma unroll
        for (int t = 0; t < 2; ++t)
#pragma unroll
            for (int r = 0; r < 4; ++r)
                out[((size_t)d * HH + h) * WW + w0 + 16 * t + rowD + r] =
                    acc[t][r] + bv;
    }
}

// ---------------------------------------------------------------------------
// Launch
// ---------------------------------------------------------------------------
extern "C" void kernel_launch(void* const* d_in, const int* in_sizes, int n_in,
                              void* d_out, int out_size, void* d_ws, size_t ws_size,
                              hipStream_t stream) {
    const float* left  = (const float*)d_in[0];
    const float* right = (const float*)d_in[1];
    const float* w0 = (const float*)d_in[2];
    const float* b0 = (const float*)d_in[3];
    const float* w1 = (const float*)d_in[4];
    const float* b1 = (const float*)d_in[5];
    const float* w2 = (const float*)d_in[6];
    const float* b2 = (const float*)d_in[7];
    const float* w3 = (const float*)d_in[8];
    const float* b3 = (const float*)d_in[9];
    const float* wf = (const float*)d_in[10];
    const float* bf = (const float*)d_in[11];

    bf16* volA = (bf16*)d_ws;
    bf16* volB = volA + PVOL;
    bf16* wb0  = volB + PVOL;
    bf16* wb1  = wb0 + 27648;
    bf16* wb2  = wb1 + 27648;
    bf16* wb3  = wb2 + 27648;
    bf16* wbf  = wb3 + 27648;   // 13824 elems
    float* Lt  = (float*)(wbf + 13824 + 32);
    float* Rt  = Lt + FEAT;

    border_zero_kernel<<<(2 * BORDER_ELEMS + 255) / 256, 256, 0, stream>>>(volA, volB);

    convert_w_mid_kernel<<<108, 256, 0, stream>>>(w0, wb0);
    convert_w_mid_kernel<<<108, 256, 0, stream>>>(w1, wb1);
    convert_w_mid_kernel<<<108, 256, 0, stream>>>(w2, wb2);
    convert_w_mid_kernel<<<108, 256, 0, stream>>>(w3, wb3);
    convert_w_final_kernel<<<54, 256, 0, stream>>>(wf, wbf);

    transpose_feat_kernel<<<dim3(WW / 32, HH), 256, 0, stream>>>(left, Lt);
    transpose_feat_kernel<<<dim3(WW / 32, HH), 256, 0, stream>>>(right, Rt);

    build_vol_kernel<<<dim3(WW / 8, HH), 256, 0, stream>>>(Lt, Rt, volA);

    int grid = DD * HH;   // 3072 blocks, one (d,h) row each
    conv_mid_kernel<<<grid, 256, 0, stream>>>(volA, wb0, b0, volB);
    conv_mid_kernel<<<grid, 256, 0, stream>>>(volB, wb1, b1, volA);
    conv_mid_kernel<<<grid, 256, 0, stream>>>(volA, wb2, b2, volB);
    conv_mid_kernel<<<grid, 256, 0, stream>>>(volB, wb3, b3, volA);
    conv_final_kernel<<<grid, 256, 0, stream>>>(volA, wbf, bf, (float*)d_out);
}

// Round 5
// 265.987 us; speedup vs baseline: 10.1338x; 1.0616x over previous
//
#include <hip/hip_runtime.h>
#include <hip/hip_bf16.h>

// Problem constants
#define HH 64
#define WW 128
#define DD 48
#define CG 8
// Padded volume layout: [d 50][w 130][h 66][c 32]  (channels-last, h inner)
#define PD 50
#define PWp 130
#define PHp 66
#define ROW 2112                               // elems per (d,w) row = 66*32
#define ROWB 4224                              // bytes per row
#define PVOL ((size_t)PD * PWp * ROW)          // 13,728,000 elems
#define FEAT ((size_t)HH * WW * 256)

typedef __hip_bfloat16 bf16;
typedef __attribute__((ext_vector_type(8))) short short8;
typedef __attribute__((ext_vector_type(4))) float f32x4;

__device__ __forceinline__ void gload_lds16(const bf16* g, bf16* l) {
    __builtin_amdgcn_global_load_lds(
        (const __attribute__((address_space(1))) unsigned int*)g,
        (__attribute__((address_space(3))) unsigned int*)l, 16, 0, 0);
}

// ---------------------------------------------------------------------------
// Border zeroing of both padded volumes (new layout)
// seg1: d slices 0,49 full; seg2: w cols 0,129 (d 1..48); seg3: h rows 0,65
// ---------------------------------------------------------------------------
#define BORDER_ELEMS 1145088
__global__ __launch_bounds__(256) void border_zero_kernel(bf16* __restrict__ volA,
                                                          bf16* __restrict__ volB) {
    size_t tid = (size_t)blockIdx.x * 256 + threadIdx.x;
    if (tid >= 2 * (size_t)BORDER_ELEMS) return;
    bf16* vol = (tid >= BORDER_ELEMS) ? volB : volA;
    size_t i = (tid >= BORDER_ELEMS) ? tid - BORDER_ELEMS : tid;
    size_t addr;
    if (i < 549120) {                       // d slices 0 and 49
        int dsl = (i < 274560) ? 0 : 49;
        size_t rem = i % 274560;
        addr = (size_t)dsl * PWp * ROW + rem;
    } else if (i < 751872) {                // w cols 0 and 129, d 1..48
        size_t j = i - 549120;
        int dd = (int)(j / 4224);
        int rr = (int)(j % 4224);
        int wcol = (rr < ROW) ? 0 : 129;
        int off = (rr < ROW) ? rr : rr - ROW;
        addr = ((size_t)(dd + 1) * PWp + wcol) * ROW + off;
    } else {                                // h rows 0 and 65, d 1..48, w 1..128
        size_t j = i - 751872;
        int dd = (int)(j >> 13);
        int rr = (int)(j & 8191);
        int w = rr >> 6;
        int e = rr & 63;
        int hrow = (e < 32) ? 0 : 65;
        addr = ((size_t)(dd + 1) * PWp + (w + 1)) * ROW + hrow * 32 + (e & 31);
    }
    vol[addr] = __float2bfloat16(0.f);
}

// ---------------------------------------------------------------------------
// Feature transpose: [256][64][128] f32 -> [64][128][256] f32
// ---------------------------------------------------------------------------
__global__ __launch_bounds__(256) void transpose_feat_kernel(
    const float* __restrict__ src, float* __restrict__ dst) {
    __shared__ float tile[32][257];
    int tid = threadIdx.x;
    int w0  = blockIdx.x * 32;
    int h   = blockIdx.y;

#pragma unroll
    for (int it = 0; it < 32; ++it) {
        int c = it * 8 + (tid >> 5);
        tile[tid & 31][c] =
            src[(size_t)c * (HH * WW) + h * WW + w0 + (tid & 31)];
    }
    __syncthreads();

    int c_l = tid & 63, wg = tid >> 6;
#pragma unroll
    for (int it = 0; it < 8; ++it) {
        int w_i = it * 4 + wg;
        float* dp = dst + ((size_t)h * WW + w0 + w_i) * 256;
#pragma unroll
        for (int cc = 0; cc < 256; cc += 64)
            dp[cc + c_l] = tile[w_i][cc + c_l];
    }
}

// ---------------------------------------------------------------------------
// Weight conversion (4 mid layers fused): fp32 [32][32][27] -> bf16 [tap][co][ci]
// ---------------------------------------------------------------------------
__global__ void convert_w_mid4_kernel(const float* __restrict__ s0,
                                      const float* __restrict__ s1,
                                      const float* __restrict__ s2,
                                      const float* __restrict__ s3,
                                      bf16* __restrict__ d0, bf16* __restrict__ d1,
                                      bf16* __restrict__ d2, bf16* __restrict__ d3) {
    int tid = blockIdx.x * 256 + threadIdx.x;
    if (tid >= 4 * 27648) return;
    int layer = tid / 27648;
    int t = tid % 27648;
    const float* src = layer == 0 ? s0 : layer == 1 ? s1 : layer == 2 ? s2 : s3;
    bf16* dst = layer == 0 ? d0 : layer == 1 ? d1 : layer == 2 ? d2 : d3;
    int tap = t >> 10, co = (t >> 5) & 31, ci = t & 31;
    dst[t] = __float2bfloat16(src[(co * 32 + ci) * 27 + tap]);
}

__global__ void convert_w_final_kernel(const float* __restrict__ src,
                                       bf16* __restrict__ dst) {
    int tid = blockIdx.x * 256 + threadIdx.x;
    if (tid >= 27 * 16 * 32) return;
    int tap = tid >> 9;
    int co  = (tid >> 5) & 15;
    int ci  = tid & 31;
    dst[tid] = (co == 0) ? __float2bfloat16(src[ci * 27 + tap])
                         : __float2bfloat16(0.f);
}

// ---------------------------------------------------------------------------
// Cost volume from channels-last features -> padded [d][w][h][c] bf16
// ---------------------------------------------------------------------------
__global__ __launch_bounds__(256) void build_vol_kernel(
    const float* __restrict__ Lt, const float* __restrict__ Rt,
    bf16* __restrict__ vol) {
    int g  = threadIdx.x & 31;
    int wq = threadIdx.x >> 5;
    int w  = blockIdx.x * 8 + wq;
    int h  = blockIdx.y;

    const float4* lp = (const float4*)(Lt + ((size_t)h * WW + w) * 256 + g * 8);
    float4 l0 = lp[0], l1 = lp[1];
    const float* Rrow = Rt + (size_t)h * WW * 256;

    bf16* outp = vol + ((size_t)1 * PWp + (w + 1)) * ROW + (h + 1) * 32 + g;
    for (int d = 0; d < DD; ++d) {
        int x = w - d;
        float s = 0.f;
        if (x >= 0) {
            const float4* rp = (const float4*)(Rrow + (size_t)x * 256 + g * 8);
            float4 r0 = rp[0], r1 = rp[1];
            s = l0.x * r0.x + l0.y * r0.y + l0.z * r0.z + l0.w * r0.w +
                l1.x * r1.x + l1.y * r1.y + l1.z * r1.z + l1.w * r1.w;
            s *= 0.125f;
        }
        outp[(size_t)d * PWp * ROW] = __float2bfloat16(s);
    }
}

// ---------------------------------------------------------------------------
// Mid conv via MFMA. Block = (d, w-quad): 512 thr / 8 waves, LDS 18 rows
// (3 dz x 6 dx) of 4224B. Wave = one w column x 32 h x 32 co.
// Bank swizzle: LDS slot s holds logical slot s ^ ((s>>3)&3)  (involution);
// staged by pre-swizzling the global source (global_load_lds dest is linear).
// ---------------------------------------------------------------------------
__global__ __launch_bounds__(512, 4) void conv_mid_kernel(
    const bf16* __restrict__ X, const bf16* __restrict__ Wb,
    const float* __restrict__ bias, bf16* __restrict__ Y) {
    __shared__ bf16 lds[18 * ROW];
    int id  = blockIdx.x;
    int swz = (id & 7) * 192 + (id >> 3);   // bijective: 1536 = 8*192
    int d  = swz >> 5;
    int q  = swz & 31;
    int w0 = q * 4;                          // padded rows start at w0
    int wv   = threadIdx.x >> 6;
    int lane = threadIdx.x & 63;

    // ---- stage 18 rows, source pre-swizzled
#pragma unroll
    for (int row = 0; row < 18; ++row) {
        int dz = row / 6, dxi = row % 6;
        const bf16* base = X + ((size_t)(d + dz) * PWp + (w0 + dxi)) * ROW;
        bf16* ldst = lds + row * ROW;
        if (wv < 4) {
            int s = wv * 64 + lane;
            int gir = s ^ ((s >> 3) & 3);
            gload_lds16(base + gir * 8, ldst + wv * 512);
        } else if (wv == 4 && lane < 8) {
            int s = 256 + lane;
            int gir = s ^ ((s >> 3) & 3);
            gload_lds16(base + gir * 8, ldst + 2048);
        }
    }
    __syncthreads();

    int wq    = wv & 3;
    int hhalf = (wv >> 2) * 32;
    int arow  = lane & 15;
    int kg    = lane >> 4;

    f32x4 acc[2][2] = {};
    const short8* Wv = (const short8*)Wb;

#pragma unroll
    for (int dz = 0; dz < 3; ++dz)
#pragma unroll
        for (int dx = 0; dx < 3; ++dx) {
            const bf16* Ar = lds + (dz * 6 + wq + dx) * ROW;
#pragma unroll
            for (int dy = 0; dy < 3; ++dy) {
                int tap = dz * 9 + dy * 3 + dx;
                short8 b0 = Wv[tap * 128 + arow * 4 + kg];
                short8 b1 = Wv[tap * 128 + 64 + arow * 4 + kg];
                int hh = hhalf + arow + dy;
                int s0 = (hh * 4 + kg) ^ ((hh >> 1) & 3);
                short8 a0 = *(const short8*)(Ar + s0 * 8);
                short8 a1 = *(const short8*)(Ar + s0 * 8 + 512); // hh+16: same XOR
                acc[0][0] = __builtin_amdgcn_mfma_f32_16x16x32_bf16(a0, b0, acc[0][0], 0, 0, 0);
                acc[0][1] = __builtin_amdgcn_mfma_f32_16x16x32_bf16(a0, b1, acc[0][1], 0, 0, 0);
                acc[1][0] = __builtin_amdgcn_mfma_f32_16x16x32_bf16(a1, b0, acc[1][0], 0, 0, 0);
                acc[1][1] = __builtin_amdgcn_mfma_f32_16x16x32_bf16(a1, b1, acc[1][1], 0, 0, 0);
            }
        }

    float bv0 = bias[arow];
    float bv1 = bias[arow + 16];
    bf16* Yp = Y + ((size_t)(d + 1) * PWp + (w0 + wq + 1)) * ROW + 32;
#pragma unroll
    for (int t = 0; t < 2; ++t)
#pragma unroll
        for (int r = 0; r < 4; ++r) {
            int o = hhalf + 16 * t + kg * 4 + r;
            float v0 = acc[t][0][r] + bv0;
            float v1 = acc[t][1][r] + bv1;
            v0 = fmaxf(v0, 0.f) + 0.2f * fminf(v0, 0.f);
            v1 = fmaxf(v1, 0.f) + 0.2f * fminf(v1, 0.f);
            Yp[o * 32 + arow]      = __float2bfloat16(v0);
            Yp[o * 32 + arow + 16] = __float2bfloat16(v1);
        }
}

// ---------------------------------------------------------------------------
// Final conv (32ch -> 1) via MFMA, same blocking. fp32 out [d][h][w].
// ---------------------------------------------------------------------------
__global__ __launch_bounds__(512, 4) void conv_final_kernel(
    const bf16* __restrict__ X, const bf16* __restrict__ Wb,
    const float* __restrict__ bias, float* __restrict__ out) {
    __shared__ bf16 lds[18 * ROW];
    int id  = blockIdx.x;
    int swz = (id & 7) * 192 + (id >> 3);
    int d  = swz >> 5;
    int q  = swz & 31;
    int w0 = q * 4;
    int wv   = threadIdx.x >> 6;
    int lane = threadIdx.x & 63;

#pragma unroll
    for (int row = 0; row < 18; ++row) {
        int dz = row / 6, dxi = row % 6;
        const bf16* base = X + ((size_t)(d + dz) * PWp + (w0 + dxi)) * ROW;
        bf16* ldst = lds + row * ROW;
        if (wv < 4) {
            int s = wv * 64 + lane;
            int gir = s ^ ((s >> 3) & 3);
            gload_lds16(base + gir * 8, ldst + wv * 512);
        } else if (wv == 4 && lane < 8) {
            int s = 256 + lane;
            int gir = s ^ ((s >> 3) & 3);
            gload_lds16(base + gir * 8, ldst + 2048);
        }
    }
    __syncthreads();

    int wq    = wv & 3;
    int hhalf = (wv >> 2) * 32;
    int arow  = lane & 15;
    int kg    = lane >> 4;

    f32x4 acc[2] = {};
    const short8* Wv = (const short8*)Wb;

#pragma unroll
    for (int dz = 0; dz < 3; ++dz)
#pragma unroll
        for (int dx = 0; dx < 3; ++dx) {
            const bf16* Ar = lds + (dz * 6 + wq + dx) * ROW;
#pragma unroll
            for (int dy = 0; dy < 3; ++dy) {
                int tap = dz * 9 + dy * 3 + dx;
                short8 b = Wv[tap * 64 + arow * 4 + kg];
                int hh = hhalf + arow + dy;
                int s0 = (hh * 4 + kg) ^ ((hh >> 1) & 3);
                short8 a0 = *(const short8*)(Ar + s0 * 8);
                short8 a1 = *(const short8*)(Ar + s0 * 8 + 512);
                acc[0] = __builtin_amdgcn_mfma_f32_16x16x32_bf16(a0, b, acc[0], 0, 0, 0);
                acc[1] = __builtin_amdgcn_mfma_f32_16x16x32_bf16(a1, b, acc[1], 0, 0, 0);
            }
        }

    if (arow == 0) {
        float bv = bias[0];
#pragma unroll
        for (int t = 0; t < 2; ++t)
#pragma unroll
            for (int r = 0; r < 4; ++r) {
                int o = hhalf + 16 * t + kg * 4 + r;
                out[((size_t)d * HH + o) * WW + (w0 + wq)] = acc[t][r] + bv;
            }
    }
}

// ---------------------------------------------------------------------------
// Launch
// ---------------------------------------------------------------------------
extern "C" void kernel_launch(void* const* d_in, const int* in_sizes, int n_in,
                              void* d_out, int out_size, void* d_ws, size_t ws_size,
                              hipStream_t stream) {
    const float* left  = (const float*)d_in[0];
    const float* right = (const float*)d_in[1];
    const float* w0 = (const float*)d_in[2];
    const float* b0 = (const float*)d_in[3];
    const float* w1 = (const float*)d_in[4];
    const float* b1 = (const float*)d_in[5];
    const float* w2 = (const float*)d_in[6];
    const float* b2 = (const float*)d_in[7];
    const float* w3 = (const float*)d_in[8];
    const float* b3 = (const float*)d_in[9];
    const float* wf = (const float*)d_in[10];
    const float* bf = (const float*)d_in[11];

    bf16* volA = (bf16*)d_ws;
    bf16* volB = volA + PVOL;
    bf16* wb0  = volB + PVOL;
    bf16* wb1  = wb0 + 27648;
    bf16* wb2  = wb1 + 27648;
    bf16* wb3  = wb2 + 27648;
    bf16* wbf  = wb3 + 27648;                 // 13824 elems
    float* Lt  = (float*)(wbf + 13824 + 32);  // 16B-aligned
    float* Rt  = Lt + FEAT;

    border_zero_kernel<<<(2 * BORDER_ELEMS + 255) / 256, 256, 0, stream>>>(volA, volB);

    convert_w_mid4_kernel<<<432, 256, 0, stream>>>(w0, w1, w2, w3, wb0, wb1, wb2, wb3);
    convert_w_final_kernel<<<54, 256, 0, stream>>>(wf, wbf);

    transpose_feat_kernel<<<dim3(WW / 32, HH), 256, 0, stream>>>(left, Lt);
    transpose_feat_kernel<<<dim3(WW / 32, HH), 256, 0, stream>>>(right, Rt);

    build_vol_kernel<<<dim3(WW / 8, HH), 256, 0, stream>>>(Lt, Rt, volA);

    int grid = DD * (WW / 4);   // 1536 blocks: (d, w-quad)
    conv_mid_kernel<<<grid, 512, 0, stream>>>(volA, wb0, b0, volB);
    conv_mid_kernel<<<grid, 512, 0, stream>>>(volB, wb1, b1, volA);
    conv_mid_kernel<<<grid, 512, 0, stream>>>(volA, wb2, b2, volB);
    conv_mid_kernel<<<grid, 512, 0, stream>>>(volB, wb3, b3, volA);
    conv_final_kernel<<<grid, 512, 0, stream>>>(volA, wbf, bf, (float*)d_out);
}

// Round 6
// 196.231 us; speedup vs baseline: 13.7362x; 1.3555x over previous
//
#include <hip/hip_runtime.h>
#include <hip/hip_bf16.h>

// Problem constants
#define HH 64
#define WW 128
#define DD 48
#define CG 8
// Padded volume layout: [d 50][w 130][h 66][c 32]  (channels-last, h inner)
#define PD 50
#define PWp 130
#define PHp 66
#define ROW 2112                               // elems per (d,w) row = 66*32
#define PVOL ((size_t)PD * PWp * ROW)          // 13,728,000 elems
#define FEAT ((size_t)HH * WW * 256)
#define SLICE_E (6 * ROW)                      // 12672 elems = 25344 B

typedef __hip_bfloat16 bf16;
typedef __attribute__((ext_vector_type(8))) short short8;
typedef __attribute__((ext_vector_type(4))) float f32x4;

__device__ __forceinline__ void gload_lds16(const bf16* g, bf16* l) {
    __builtin_amdgcn_global_load_lds(
        (const __attribute__((address_space(1))) unsigned int*)g,
        (__attribute__((address_space(3))) unsigned int*)l, 16, 0, 0);
}

// ---------------------------------------------------------------------------
// Border zeroing of both padded volumes
// ---------------------------------------------------------------------------
#define BORDER_ELEMS 1145088
__global__ __launch_bounds__(256) void border_zero_kernel(bf16* __restrict__ volA,
                                                          bf16* __restrict__ volB) {
    size_t tid = (size_t)blockIdx.x * 256 + threadIdx.x;
    if (tid >= 2 * (size_t)BORDER_ELEMS) return;
    bf16* vol = (tid >= BORDER_ELEMS) ? volB : volA;
    size_t i = (tid >= BORDER_ELEMS) ? tid - BORDER_ELEMS : tid;
    size_t addr;
    if (i < 549120) {                       // d slices 0 and 49
        int dsl = (i < 274560) ? 0 : 49;
        size_t rem = i % 274560;
        addr = (size_t)dsl * PWp * ROW + rem;
    } else if (i < 751872) {                // w cols 0 and 129, d 1..48
        size_t j = i - 549120;
        int dd = (int)(j / 4224);
        int rr = (int)(j % 4224);
        int wcol = (rr < ROW) ? 0 : 129;
        int off = (rr < ROW) ? rr : rr - ROW;
        addr = ((size_t)(dd + 1) * PWp + wcol) * ROW + off;
    } else {                                // h rows 0 and 65, d 1..48, w 1..128
        size_t j = i - 751872;
        int dd = (int)(j >> 13);
        int rr = (int)(j & 8191);
        int w = rr >> 6;
        int e = rr & 63;
        int hrow = (e < 32) ? 0 : 65;
        addr = ((size_t)(dd + 1) * PWp + (w + 1)) * ROW + hrow * 32 + (e & 31);
    }
    vol[addr] = __float2bfloat16(0.f);
}

// ---------------------------------------------------------------------------
// Feature transpose: [256][64][128] f32 -> [64][128][256] f32
// ---------------------------------------------------------------------------
__global__ __launch_bounds__(256) void transpose_feat_kernel(
    const float* __restrict__ src, float* __restrict__ dst) {
    __shared__ float tile[32][257];
    int tid = threadIdx.x;
    int w0  = blockIdx.x * 32;
    int h   = blockIdx.y;

#pragma unroll
    for (int it = 0; it < 32; ++it) {
        int c = it * 8 + (tid >> 5);
        tile[tid & 31][c] =
            src[(size_t)c * (HH * WW) + h * WW + w0 + (tid & 31)];
    }
    __syncthreads();

    int c_l = tid & 63, wg = tid >> 6;
#pragma unroll
    for (int it = 0; it < 8; ++it) {
        int w_i = it * 4 + wg;
        float* dp = dst + ((size_t)h * WW + w0 + w_i) * 256;
#pragma unroll
        for (int cc = 0; cc < 256; cc += 64)
            dp[cc + c_l] = tile[w_i][cc + c_l];
    }
}

// ---------------------------------------------------------------------------
// Weight conversion (4 mid layers fused): fp32 [32][32][27] -> bf16 [tap][co][ci]
// ---------------------------------------------------------------------------
__global__ void convert_w_mid4_kernel(const float* __restrict__ s0,
                                      const float* __restrict__ s1,
                                      const float* __restrict__ s2,
                                      const float* __restrict__ s3,
                                      bf16* __restrict__ d0, bf16* __restrict__ d1,
                                      bf16* __restrict__ d2, bf16* __restrict__ d3) {
    int tid = blockIdx.x * 256 + threadIdx.x;
    if (tid >= 4 * 27648) return;
    int layer = tid / 27648;
    int t = tid % 27648;
    const float* src = layer == 0 ? s0 : layer == 1 ? s1 : layer == 2 ? s2 : s3;
    bf16* dst = layer == 0 ? d0 : layer == 1 ? d1 : layer == 2 ? d2 : d3;
    int tap = t >> 10, co = (t >> 5) & 31, ci = t & 31;
    dst[t] = __float2bfloat16(src[(co * 32 + ci) * 27 + tap]);
}

__global__ void convert_w_final_kernel(const float* __restrict__ src,
                                       bf16* __restrict__ dst) {
    int tid = blockIdx.x * 256 + threadIdx.x;
    if (tid >= 27 * 16 * 32) return;
    int tap = tid >> 9;
    int co  = (tid >> 5) & 15;
    int ci  = tid & 31;
    dst[tid] = (co == 0) ? __float2bfloat16(src[ci * 27 + tap])
                         : __float2bfloat16(0.f);
}

// ---------------------------------------------------------------------------
// Cost volume from channels-last features -> padded [d][w][h][c] bf16
// ---------------------------------------------------------------------------
__global__ __launch_bounds__(256) void build_vol_kernel(
    const float* __restrict__ Lt, const float* __restrict__ Rt,
    bf16* __restrict__ vol) {
    int g  = threadIdx.x & 31;
    int wq = threadIdx.x >> 5;
    int w  = blockIdx.x * 8 + wq;
    int h  = blockIdx.y;

    const float4* lp = (const float4*)(Lt + ((size_t)h * WW + w) * 256 + g * 8);
    float4 l0 = lp[0], l1 = lp[1];
    const float* Rrow = Rt + (size_t)h * WW * 256;

    bf16* outp = vol + ((size_t)1 * PWp + (w + 1)) * ROW + (h + 1) * 32 + g;
    for (int d = 0; d < DD; ++d) {
        int x = w - d;
        float s = 0.f;
        if (x >= 0) {
            const float4* rp = (const float4*)(Rrow + (size_t)x * 256 + g * 8);
            float4 r0 = rp[0], r1 = rp[1];
            s = l0.x * r0.x + l0.y * r0.y + l0.z * r0.z + l0.w * r0.w +
                l1.x * r1.x + l1.y * r1.y + l1.z * r1.z + l1.w * r1.w;
            s *= 0.125f;
        }
        outp[(size_t)d * PWp * ROW] = __float2bfloat16(s);
    }
}

// ---------------------------------------------------------------------------
// Mid conv, pipelined d-walk. Block = 256 thr / 4 waves = (w-quad, d-segment
// of 3). LDS ring: 3 slices x 6 rows x 4224 B = 76032 B -> 2 blocks/CU.
// Wave: one w column, M=64 (all h, 4 M-tiles), N=32. Per step: compute from
// ring, then stage ONE new slice (25 KB) into the freed slot.
// Swizzle (involution f(s)=s^((s>>3)&3)) applied on global source; reads use
// slot = (hh*4+kg)^((hh>>1)&3). Verified in r5 (0 bank conflicts).
// ---------------------------------------------------------------------------
__global__ __launch_bounds__(256, 2) void conv_mid_kernel(
    const bf16* __restrict__ X, const bf16* __restrict__ Wb,
    const float* __restrict__ bias, bf16* __restrict__ Y) {
    __shared__ bf16 lds[3 * SLICE_E];
    int id   = blockIdx.x;
    int xcd  = id & 7;
    int r    = id >> 3;                  // 0..63
    int wq   = r & 31;
    int dseg = xcd * 2 + (r >> 5);       // blocks sharing slices land on same XCD
    int w0   = wq * 4;
    int d0   = dseg * 3;
    int tid  = threadIdx.x;
    int wv   = tid >> 6;
    int lane = tid & 63;
    int arow = lane & 15;
    int kg   = lane >> 4;

    auto stage = [&](int dslice, bf16* dst) {
#pragma unroll
        for (int row = 0; row < 6; ++row) {
            const bf16* base = X + ((size_t)dslice * PWp + (w0 + row)) * ROW;
            int s = wv * 64 + lane;
            int gir = s ^ ((s >> 3) & 3);
            gload_lds16(base + gir * 8, dst + row * ROW + wv * 512);
            if (tid < 8) {
                int s2 = 256 + lane;
                int gir2 = s2 ^ ((s2 >> 3) & 3);
                gload_lds16(base + gir2 * 8, dst + row * ROW + 2048);
            }
        }
    };

    bf16* p0 = lds;
    bf16* p1 = lds + SLICE_E;
    bf16* p2 = lds + 2 * SLICE_E;
    stage(d0 + 0, p0);
    stage(d0 + 1, p1);
    stage(d0 + 2, p2);
    __syncthreads();

    const short8* Wv = (const short8*)Wb;
    float bv0 = bias[arow];
    float bv1 = bias[arow + 16];

    for (int i = 0; i < 3; ++i) {
        f32x4 acc[4][2] = {};
#pragma unroll
        for (int dz = 0; dz < 3; ++dz) {
            const bf16* P = (dz == 0) ? p0 : (dz == 1) ? p1 : p2;
#pragma unroll
            for (int dx = 0; dx < 3; ++dx) {
                const bf16* Ar = P + (wv + dx) * ROW;
#pragma unroll
                for (int dy = 0; dy < 3; ++dy) {
                    int tap = dz * 9 + dy * 3 + dx;
                    short8 b0 = Wv[tap * 128 + arow * 4 + kg];
                    short8 b1 = Wv[tap * 128 + 64 + arow * 4 + kg];
                    int hh = arow + dy;
                    int s0 = (hh * 4 + kg) ^ ((hh >> 1) & 3);
#pragma unroll
                    for (int t = 0; t < 4; ++t) {
                        short8 a = *(const short8*)(Ar + s0 * 8 + t * 512);
                        acc[t][0] = __builtin_amdgcn_mfma_f32_16x16x32_bf16(
                            a, b0, acc[t][0], 0, 0, 0);
                        acc[t][1] = __builtin_amdgcn_mfma_f32_16x16x32_bf16(
                            a, b1, acc[t][1], 0, 0, 0);
                    }
                }
            }
        }
        __syncthreads();                       // all waves done reading p0
        if (i < 2) stage(d0 + i + 3, p0);      // refill freed slot

        int d = d0 + i;
        bf16* Yp = Y + (((size_t)(d + 1) * PWp + (w0 + wv + 1))) * ROW + 32;
#pragma unroll
        for (int t = 0; t < 4; ++t)
#pragma unroll
            for (int rr = 0; rr < 4; ++rr) {
                int o = t * 16 + kg * 4 + rr;
                float v0 = acc[t][0][rr] + bv0;
                float v1 = acc[t][1][rr] + bv1;
                v0 = fmaxf(v0, 0.f) + 0.2f * fminf(v0, 0.f);
                v1 = fmaxf(v1, 0.f) + 0.2f * fminf(v1, 0.f);
                Yp[o * 32 + arow]      = __float2bfloat16(v0);
                Yp[o * 32 + arow + 16] = __float2bfloat16(v1);
            }
        __syncthreads();                       // staged slice landed
        bf16* tswap = p0; p0 = p1; p1 = p2; p2 = tswap;
    }
}

// ---------------------------------------------------------------------------
// Final conv (32ch -> 1), same pipelined structure. fp32 out [d][h][w].
// ---------------------------------------------------------------------------
__global__ __launch_bounds__(256, 2) void conv_final_kernel(
    const bf16* __restrict__ X, const bf16* __restrict__ Wb,
    const float* __restrict__ bias, float* __restrict__ out) {
    __shared__ bf16 lds[3 * SLICE_E];
    int id   = blockIdx.x;
    int xcd  = id & 7;
    int r    = id >> 3;
    int wq   = r & 31;
    int dseg = xcd * 2 + (r >> 5);
    int w0   = wq * 4;
    int d0   = dseg * 3;
    int tid  = threadIdx.x;
    int wv   = tid >> 6;
    int lane = tid & 63;
    int arow = lane & 15;
    int kg   = lane >> 4;

    auto stage = [&](int dslice, bf16* dst) {
#pragma unroll
        for (int row = 0; row < 6; ++row) {
            const bf16* base = X + ((size_t)dslice * PWp + (w0 + row)) * ROW;
            int s = wv * 64 + lane;
            int gir = s ^ ((s >> 3) & 3);
            gload_lds16(base + gir * 8, dst + row * ROW + wv * 512);
            if (tid < 8) {
                int s2 = 256 + lane;
                int gir2 = s2 ^ ((s2 >> 3) & 3);
                gload_lds16(base + gir2 * 8, dst + row * ROW + 2048);
            }
        }
    };

    bf16* p0 = lds;
    bf16* p1 = lds + SLICE_E;
    bf16* p2 = lds + 2 * SLICE_E;
    stage(d0 + 0, p0);
    stage(d0 + 1, p1);
    stage(d0 + 2, p2);
    __syncthreads();

    const short8* Wv = (const short8*)Wb;
    float bv = bias[0];

    for (int i = 0; i < 3; ++i) {
        f32x4 acc[4] = {};
#pragma unroll
        for (int dz = 0; dz < 3; ++dz) {
            const bf16* P = (dz == 0) ? p0 : (dz == 1) ? p1 : p2;
#pragma unroll
            for (int dx = 0; dx < 3; ++dx) {
                const bf16* Ar = P + (wv + dx) * ROW;
#pragma unroll
                for (int dy = 0; dy < 3; ++dy) {
                    int tap = dz * 9 + dy * 3 + dx;
                    short8 b = Wv[tap * 64 + arow * 4 + kg];
                    int hh = arow + dy;
                    int s0 = (hh * 4 + kg) ^ ((hh >> 1) & 3);
#pragma unroll
                    for (int t = 0; t < 4; ++t) {
                        short8 a = *(const short8*)(Ar + s0 * 8 + t * 512);
                        acc[t] = __builtin_amdgcn_mfma_f32_16x16x32_bf16(
                            a, b, acc[t], 0, 0, 0);
                    }
                }
            }
        }
        __syncthreads();
        if (i < 2) stage(d0 + i + 3, p0);

        if (arow == 0) {
            int d = d0 + i;
#pragma unroll
            for (int t = 0; t < 4; ++t)
#pragma unroll
                for (int rr = 0; rr < 4; ++rr) {
                    int o = t * 16 + kg * 4 + rr;
                    out[((size_t)d * HH + o) * WW + (w0 + wv)] = acc[t][rr] + bv;
                }
        }
        __syncthreads();
        bf16* tswap = p0; p0 = p1; p1 = p2; p2 = tswap;
    }
}

// ---------------------------------------------------------------------------
// Launch
// ---------------------------------------------------------------------------
extern "C" void kernel_launch(void* const* d_in, const int* in_sizes, int n_in,
                              void* d_out, int out_size, void* d_ws, size_t ws_size,
                              hipStream_t stream) {
    const float* left  = (const float*)d_in[0];
    const float* right = (const float*)d_in[1];
    const float* w0 = (const float*)d_in[2];
    const float* b0 = (const float*)d_in[3];
    const float* w1 = (const float*)d_in[4];
    const float* b1 = (const float*)d_in[5];
    const float* w2 = (const float*)d_in[6];
    const float* b2 = (const float*)d_in[7];
    const float* w3 = (const float*)d_in[8];
    const float* b3 = (const float*)d_in[9];
    const float* wf = (const float*)d_in[10];
    const float* bf = (const float*)d_in[11];

    bf16* volA = (bf16*)d_ws;
    bf16* volB = volA + PVOL;
    bf16* wb0  = volB + PVOL;
    bf16* wb1  = wb0 + 27648;
    bf16* wb2  = wb1 + 27648;
    bf16* wb3  = wb2 + 27648;
    bf16* wbf  = wb3 + 27648;                 // 13824 elems
    float* Lt  = (float*)(wbf + 13824 + 32);  // 16B-aligned
    float* Rt  = Lt + FEAT;

    border_zero_kernel<<<(2 * BORDER_ELEMS + 255) / 256, 256, 0, stream>>>(volA, volB);

    convert_w_mid4_kernel<<<432, 256, 0, stream>>>(w0, w1, w2, w3, wb0, wb1, wb2, wb3);
    convert_w_final_kernel<<<54, 256, 0, stream>>>(wf, wbf);

    transpose_feat_kernel<<<dim3(WW / 32, HH), 256, 0, stream>>>(left, Lt);
    transpose_feat_kernel<<<dim3(WW / 32, HH), 256, 0, stream>>>(right, Rt);

    build_vol_kernel<<<dim3(WW / 8, HH), 256, 0, stream>>>(Lt, Rt, volA);

    int grid = 512;   // 32 w-quads x 16 d-segments, all-resident (2 blocks/CU)
    conv_mid_kernel<<<grid, 256, 0, stream>>>(volA, wb0, b0, volB);
    conv_mid_kernel<<<grid, 256, 0, stream>>>(volB, wb1, b1, volA);
    conv_mid_kernel<<<grid, 256, 0, stream>>>(volA, wb2, b2, volB);
    conv_mid_kernel<<<grid, 256, 0, stream>>>(volB, wb3, b3, volA);
    conv_final_kernel<<<grid, 256, 0, stream>>>(volA, wbf, bf, (float*)d_out);
}